// Round 6
// baseline (1369.807 us; speedup 1.0000x reference)
//
#include <hip/hip_runtime.h>
#include <math.h>

#define BS   256
#define NN   255
#define DIM  128
#define GAMMA 0.07
#define NUM_ITERS 1000

__device__ __forceinline__ double wred_d(double v) {
  #pragma unroll
  for (int k = 1; k < 64; k <<= 1) v += __shfl_xor(v, k, 64);
  return v;
}
__device__ __forceinline__ int wred_i(int v) {
  #pragma unroll
  for (int k = 1; k < 64; k <<= 1) v += __shfl_xor(v, k, 64);
  return v;
}

// lane-uniform float readlane (result in SGPR)
__device__ __forceinline__ float RLF(float v, int lane) {
  return __int_as_float(__builtin_amdgcn_readlane(__float_as_int(v), lane));
}

// DPP wave64 sum -> total broadcast via readlane(63). VALU-only.
template <int CTRL, int RMASK>
__device__ __forceinline__ float dpp_add(float x) {
  int t = __builtin_amdgcn_update_dpp(0, __float_as_int(x), CTRL, RMASK, 0xf, true);
  return x + __int_as_float(t);
}
__device__ __forceinline__ float wred64_dpp(float x) {
  x = dpp_add<0x111, 0xf>(x);   // row_shr:1
  x = dpp_add<0x112, 0xf>(x);   // row_shr:2
  x = dpp_add<0x114, 0xf>(x);   // row_shr:4
  x = dpp_add<0x118, 0xf>(x);   // row_shr:8
  x = dpp_add<0x142, 0xa>(x);   // row_bcast:15
  x = dpp_add<0x143, 0xc>(x);   // row_bcast:31; lane63 = total
  return RLF(x, 63);
}

// Forced codegen: v_fmac_f32 acc, s(y), v(k) — src0=SGPR broadcast, vsrc1=VGPR.
// The "v" constraints pin kreg into arch VGPRs at every use (R5: compiler put
// kreg in AGPRs -> per-FMA mov tax; VGPR_Count=56 was the tell).
__device__ __forceinline__ void fmac_row(float4& acc, const float4& k, float ys) {
  asm volatile(
    "v_fmac_f32 %0, %8, %4\n\t"
    "v_fmac_f32 %1, %8, %5\n\t"
    "v_fmac_f32 %2, %8, %6\n\t"
    "v_fmac_f32 %3, %8, %7"
    : "+v"(acc.x), "+v"(acc.y), "+v"(acc.z), "+v"(acc.w)
    : "v"(k.x), "v"(k.y), "v"(k.z), "v"(k.w), "s"(ys));
}

// ---------------- kernel 1: normalized features, stored transposed fp64 ----------------
__global__ void k_ftr(const float* __restrict__ z, double* __restrict__ ftrT) {
  int b = blockIdx.x;
  int d = threadIdx.x;
  double z0 = (double)z[b * 256 + d];
  double z1 = (double)z[b * 256 + 128 + d];
  double n = sqrt(z0 * z0 + z1 * z1);
  n = fmax(n, 1e-12);
  ftrT[d * 512 + b]       = z0 / n;
  ftrT[d * 512 + 256 + b] = z1 / n;
}

// ---------------- kernel 2: K = exp(-gamma * dist), fp64 math, fp32 store ----------------
__global__ void k_K(const double* __restrict__ ftrT, float* __restrict__ K,
                    double* __restrict__ pk_knt, double* __restrict__ pos_arr) {
  int i = blockIdx.x;
  int t = threadIdx.x;
  __shared__ double rowi[DIM];
  __shared__ double redd[4];
  if (t < DIM) rowi[t] = ftrT[t * 512 + i];
  __syncthreads();
  double xn = 0.0;
  #pragma unroll 8
  for (int d = 0; d < DIM; ++d) xn += rowi[d] * rowi[d];

  double knt_part = 0.0;
  #pragma unroll
  for (int h = 0; h < 2; ++h) {
    int j = t + h * 256;
    double dot = 0.0, sq = 0.0;
    #pragma unroll 8
    for (int d = 0; d < DIM; ++d) {
      double f = ftrT[d * 512 + j];
      dot += rowi[d] * f;
      sq  += f * f;
    }
    double dist = xn + sq - 2.0 * dot;
    double kv = exp(-GAMMA * dist);
    K[i * 512 + j] = (float)kv;
    if (h == 1) {
      if (j == 256 + i) pos_arr[i] = kv;
      else knt_part += kv;
    }
  }
  double w = wred_d(knt_part);
  if ((t & 63) == 0) redd[t >> 6] = w;
  __syncthreads();
  if (t == 0) pk_knt[i] = redd[0] + redd[1] + redd[2] + redd[3];
}

// ---------------- kernel 3: per-batch PGD ----------------
// 16 waves. Wave rg owns KK rows [16rg,16rg+16), lane l cols [4l,4l+4) in
// VGPR-pinned registers. All solver state (float4/lane) lives in wave 0 with
// DPP in-register reductions; 2 barriers/iter.
__global__ __launch_bounds__(1024, 4) void k_pgd(
    const float* __restrict__ K, const float* __restrict__ alpha_init,
    double* __restrict__ neg_arr, double* __restrict__ sa_arr,
    int* __restrict__ cnt1, int* __restrict__ cntp, int* __restrict__ cnt0) {
  int r = blockIdx.x;
  int tid = threadIdx.x;
  int l = tid & 63;
  int rg = tid >> 6;

  __shared__ __align__(16) float ytil[BS];        // a-indexed, ytil[r] == 0 always
  __shared__ __align__(16) float part[16 * BS];   // part[rowgroup][a-col]

  // KK block: rows 16rg+j, cols 4l..4l+3; pin to make values opaque (no remat)
  float4 kreg[16];
  #pragma unroll
  for (int j = 0; j < 16; ++j)
    kreg[j] = *(const float4*)&K[(rg * 16 + j) * 512 + 4 * l];
  #pragma unroll
  for (int j = 0; j < 16; ++j)
    asm volatile("" : "+v"(kreg[j].x), "+v"(kreg[j].y), "+v"(kreg[j].z), "+v"(kreg[j].w));

  // wave-0 state: lane l owns state cols c = 4l..4l+3 (c < 255)
  int c0 = 4 * l;
  float a0v = 0.f, a1v = 0.f, a2v = 0.f, a3v = 0.f;        // alpha
  float p0 = 0.f, p1 = 0.f, p2 = 0.f, p3 = 0.f;            // alpha_prev
  float y0 = 0.f, y1 = 0.f, y2 = 0.f, y3 = 0.f;            // y
  float k0 = 0.f, k1 = 0.f, k2 = 0.f, k3 = 0.f;            // 1 - K[r][a(c)]
  float S = 0.f;

  if (rg == 0) {
    #pragma unroll
    for (int k = 0; k < 4; ++k) {
      int c = c0 + k;
      if (c < NN) {
        float av = alpha_init[r * NN + c];
        av = fminf(fmaxf(av, 0.f), 1.f);
        int a = c + (c >= r ? 1 : 0);
        float kr = 1.0f - K[r * 512 + a];
        if (k == 0) { a0v = av; p0 = av; y0 = av; k0 = kr; }
        if (k == 1) { a1v = av; p1 = av; y1 = av; k1 = kr; }
        if (k == 2) { a2v = av; p2 = av; y2 = av; k2 = kr; }
        if (k == 3) { a3v = av; p3 = av; y3 = av; k3 = kr; }
      }
    }
    float4 zz = {0.f, 0.f, 0.f, 0.f};
    *(float4*)&ytil[4 * l] = zz;
    if (c0 + 0 < NN) ytil[c0 + 0 + (c0 + 0 >= r ? 1 : 0)] = y0;
    if (c0 + 1 < NN) ytil[c0 + 1 + (c0 + 1 >= r ? 1 : 0)] = y1;
    if (c0 + 2 < NN) ytil[c0 + 2 + (c0 + 2 >= r ? 1 : 0)] = y2;
    if (c0 + 3 < NN) ytil[c0 + 3 + (c0 + 3 >= r ? 1 : 0)] = y3;
    S = wred64_dpp(y0 + y1 + y2 + y3);
  }

  for (int it = 0; it < NUM_ITERS; ++it) {
    __syncthreads();                 // B1: ytil for this iter visible

    // matvec: one broadcast b128 (lanes 0-3 carry the wave's 16 y's),
    // readlane -> SGPR, forced v_fmac(acc, s, v)
    float4 q = *(const float4*)&ytil[rg * 16 + 4 * (l & 3)];
    float4 acc = {0.f, 0.f, 0.f, 0.f};
    #pragma unroll
    for (int jq = 0; jq < 4; ++jq) {
      float vx = RLF(q.x, jq), vy = RLF(q.y, jq), vz = RLF(q.z, jq), vw = RLF(q.w, jq);
      fmac_row(acc, kreg[4*jq+0], vx);
      fmac_row(acc, kreg[4*jq+1], vy);
      fmac_row(acc, kreg[4*jq+2], vz);
      fmac_row(acc, kreg[4*jq+3], vw);
    }
    *(float4*)&part[rg * 256 + 4 * l] = acc;
    __syncthreads();                 // B2: partials visible

    if (rg == 0) {
      // full column sums over a-cols 4l..4l+3
      float4 gA = {0.f, 0.f, 0.f, 0.f};
      #pragma unroll
      for (int j = 0; j < 16; ++j) {
        float4 p = *(const float4*)&part[j * 256 + 4 * l];
        gA.x += p.x; gA.y += p.y; gA.z += p.z; gA.w += p.w;
      }
      // g~[r]
      int rq = r >> 2, rc = r & 3;
      float cv = (rc == 0) ? gA.x : (rc == 1) ? gA.y : (rc == 2) ? gA.z : gA.w;
      float gr = RLF(cv, rq);
      float nxt = __shfl_down(gA.x, 1, 64);
      float g0 = ((c0 + 0 < r) ? gA.x : gA.y) + k0 * S + 0.1f * y0 - gr - 2.0f;
      float g1 = ((c0 + 1 < r) ? gA.y : gA.z) + k1 * S + 0.1f * y1 - gr - 2.0f;
      float g2 = ((c0 + 2 < r) ? gA.z : gA.w) + k2 * S + 0.1f * y2 - gr - 2.0f;
      float g3 = ((c0 + 3 < r) ? gA.w : nxt)  + k3 * S + 0.1f * y3 - gr - 2.0f;
      if (c0 + 3 >= NN) g3 = 0.f;
      float n2 = wred64_dpp(g0 * g0 + g1 * g1 + g2 * g2 + g3 * g3);
      float sinv = 0.001f / (sqrtf(n2) + 1e-12f);   // single divide
      float na0 = fminf(fmaxf(y0 - g0 * sinv, 0.f), 1.f);
      float na1 = fminf(fmaxf(y1 - g1 * sinv, 0.f), 1.f);
      float na2 = fminf(fmaxf(y2 - g2 * sinv, 0.f), 1.f);
      float na3 = fminf(fmaxf(y3 - g3 * sinv, 0.f), 1.f);
      p0 = a0v; p1 = a1v; p2 = a2v; p3 = a3v;
      a0v = na0; a1v = na1; a2v = na2; a3v = na3;
      float tt = (float)(it + 1);
      float beta = tt / (tt + 3.0f);
      y0 = a0v + beta * (a0v - p0);
      y1 = a1v + beta * (a1v - p1);
      y2 = a2v + beta * (a2v - p2);
      y3 = a3v + beta * (a3v - p3);
      if (c0 + 0 < NN) ytil[c0 + 0 + (c0 + 0 >= r ? 1 : 0)] = y0;
      if (c0 + 1 < NN) ytil[c0 + 1 + (c0 + 1 >= r ? 1 : 0)] = y1;
      if (c0 + 2 < NN) ytil[c0 + 2 + (c0 + 2 >= r ? 1 : 0)] = y2;
      if (c0 + 3 < NN) ytil[c0 + 3 + (c0 + 3 >= r ? 1 : 0)] = y3;
      S = wred64_dpp(y0 + y1 + y2 + y3);
    }
  }

  // epilogue: wave 0 holds all state — single-wave fp64 reductions
  if (rg == 0) {
    double nl = 0.0, sa = 0.0;
    int c1 = 0, cp = 0, cz = 0;
    float av[4] = {a0v, a1v, a2v, a3v};
    #pragma unroll
    for (int k = 0; k < 4; ++k) {
      int c = c0 + k;
      if (c < NN) {
        int a = c + (c >= r ? 1 : 0);
        float kx = K[a * 512 + 256 + r];       // KnT[r,c]
        nl += (double)av[k] * (double)kx;
        sa += (double)av[k];
        c1 += (av[k] == 1.0f);
        cp += (av[k] > 0.0f);
        cz += (av[k] == 0.0f);
      }
    }
    nl = wred_d(nl); sa = wred_d(sa);
    c1 = wred_i(c1); cp = wred_i(cp); cz = wred_i(cz);
    if (l == 0) {
      neg_arr[r] = nl;
      sa_arr[r]  = sa;
      cnt1[r] = c1; cntp[r] = cp; cnt0[r] = cz;
    }
  }
}

// ---------------- kernel 4: final reduction to the 6 scalar outputs ----------------
__global__ void k_fin(const double* __restrict__ pk_knt, const double* __restrict__ pos_arr,
                      const double* __restrict__ neg_arr, const double* __restrict__ sa_arr,
                      const int* __restrict__ cnt1, const int* __restrict__ cntp,
                      const int* __restrict__ cnt0, float* __restrict__ out) {
  int t = threadIdx.x;  // 256
  __shared__ double rd[16];
  __shared__ int ri[12];
  double knt = pk_knt[t];
  double pos = pos_arr[t];
  double neg = neg_arr[t];
  double pl  = sa_arr[t] * pos_arr[t];
  int a1 = cnt1[t], ap = cntp[t], a0 = cnt0[t];
  knt = wred_d(knt); pos = wred_d(pos); neg = wred_d(neg); pl = wred_d(pl);
  a1 = wred_i(a1); ap = wred_i(ap); a0 = wred_i(a0);
  int w = t >> 6;
  if ((t & 63) == 0) {
    rd[w] = knt; rd[4 + w] = pos; rd[8 + w] = neg; rd[12 + w] = pl;
    ri[w] = a1; ri[4 + w] = ap; ri[8 + w] = a0;
  }
  __syncthreads();
  if (t == 0) {
    double kntS = rd[0] + rd[1] + rd[2] + rd[3];
    double posS = rd[4] + rd[5] + rd[6] + rd[7];
    double negS = rd[8] + rd[9] + rd[10] + rd[11];
    double plS  = rd[12] + rd[13] + rd[14] + rd[15];
    int c1t = ri[0] + ri[1] + ri[2] + ri[3];
    int cpt = ri[4] + ri[5] + ri[6] + ri[7];
    int c0t = ri[8] + ri[9] + ri[10] + ri[11];
    out[0] = (float)(negS / 256.0 - plS / 256.0);
    out[1] = (float)(posS / 256.0);
    out[2] = (float)(kntS / (256.0 * 255.0));
    out[3] = (float)c1t / ((float)cpt + 1e-10f);
    out[4] = (float)c0t / 65280.0f;
    out[5] = 0.0f;
  }
}

extern "C" void kernel_launch(void* const* d_in, const int* in_sizes, int n_in,
                              void* d_out, int out_size, void* d_ws, size_t ws_size,
                              hipStream_t stream) {
  const float* z     = (const float*)d_in[0];
  const float* ainit = (const float*)d_in[1];
  char* ws = (char*)d_ws;
  double* ftrT   = (double*)ws;                       // 512 KB
  float*  K      = (float*)(ws + 524288);             // 512 KB
  double* pk_knt = (double*)(ws + 1048576);
  double* pos_a  = (double*)(ws + 1048576 + 2048);
  double* neg_a  = (double*)(ws + 1048576 + 4096);
  double* sa_a   = (double*)(ws + 1048576 + 6144);
  int* cnt1 = (int*)(ws + 1048576 + 8192);
  int* cntp = (int*)(ws + 1048576 + 8192 + 1024);
  int* cnt0 = (int*)(ws + 1048576 + 8192 + 2048);
  float* out = (float*)d_out;

  k_ftr<<<256, 128, 0, stream>>>(z, ftrT);
  k_K  <<<256, 256, 0, stream>>>(ftrT, K, pk_knt, pos_a);
  k_pgd<<<256, 1024, 0, stream>>>(K, ainit, neg_a, sa_a, cnt1, cntp, cnt0);
  k_fin<<<1, 256, 0, stream>>>(pk_knt, pos_a, neg_a, sa_a, cnt1, cntp, cnt0, out);
}